// Round 3
// baseline (125.573 us; speedup 1.0000x reference)
//
#include <hip/hip_runtime.h>

constexpr int BB = 16;     // batch
constexpr int CC = 512;    // channels
constexpr int PP = 32;     // clusters
constexpr int NN = 4096;   // H*W

// ---------------------------------------------------------------------------
// prep: beta = sigmoid(sf), rbeta = 1/beta, csq[p] = |centers_p|^2
// ---------------------------------------------------------------------------
__global__ __launch_bounds__(64) void prep_kernel(
    const float* __restrict__ w, const float* __restrict__ sf,
    float* __restrict__ beta, float* __restrict__ rbeta,
    float* __restrict__ csq) {
  int p = blockIdx.x;
  int t = threadIdx.x;
  float s = 0.f;
  for (int i = t; i < CC; i += 64) {
    float v = w[p * CC + i];
    s = fmaf(v, v, s);
  }
#pragma unroll
  for (int off = 32; off; off >>= 1) s += __shfl_down(s, off);
  if (t == 0) {
    csq[p] = s;
    float e = __expf(-sf[p]);
    rbeta[p] = 1.f + e;            // 1/beta
    beta[p] = 1.f / (1.f + e);     // beta
  }
}

// ---------------------------------------------------------------------------
// assign: grid 256 (16 b x 16 tiles of 256 px), block 512 = 8 waves.
// Wave wv owns p in [4wv,4wv+4); each thread owns 4 px (float4 loads).
// Centers staged once in LDS transposed [c][p]. Cross-wave softmax via
// padded LDS reduce. Also accumulates sum_ass via atomics (fused).
// ---------------------------------------------------------------------------
__global__ __launch_bounds__(512) void assign_kernel(
    const float* __restrict__ x, const float* __restrict__ w,
    const float* __restrict__ rbeta, const float* __restrict__ csq,
    float* __restrict__ assign_out, float* __restrict__ sum_ass) {
  __shared__ float cent[CC][36];    // [c][p] pad 36 -> 73.7 KB, f4-aligned
  __shared__ float redA[8][64][5];  // max partials (pad 5: conflict-free)
  __shared__ float redB[8][64][5];  // sum partials

  int tid = threadIdx.x;
  int wv = tid >> 6, lane = tid & 63;

  for (int i = tid; i < PP * CC; i += 512) {
    int p = i >> 9, c = i & (CC - 1);
    cent[c][p] = w[i];
  }
  __syncthreads();

  int b = blockIdx.x >> 4;
  int n0 = (blockIdx.x & 15) << 8;
  const float4* xb = (const float4*)(x + (size_t)b * CC * NN + n0) + lane;
  int p0 = wv << 2;

  float acc[4][4];  // [j = p offset][q = px]
#pragma unroll
  for (int j = 0; j < 4; ++j)
#pragma unroll
    for (int q = 0; q < 4; ++q) acc[j][q] = 0.f;
  float xsq[4] = {0.f, 0.f, 0.f, 0.f};

#pragma unroll 4
  for (int c = 0; c < CC; ++c) {
    float4 xv = xb[(size_t)c * (NN / 4)];
    float4 cv = *(const float4*)&cent[c][p0];  // broadcast
    xsq[0] = fmaf(xv.x, xv.x, xsq[0]);
    xsq[1] = fmaf(xv.y, xv.y, xsq[1]);
    xsq[2] = fmaf(xv.z, xv.z, xsq[2]);
    xsq[3] = fmaf(xv.w, xv.w, xsq[3]);
    acc[0][0] = fmaf(cv.x, xv.x, acc[0][0]);
    acc[0][1] = fmaf(cv.x, xv.y, acc[0][1]);
    acc[0][2] = fmaf(cv.x, xv.z, acc[0][2]);
    acc[0][3] = fmaf(cv.x, xv.w, acc[0][3]);
    acc[1][0] = fmaf(cv.y, xv.x, acc[1][0]);
    acc[1][1] = fmaf(cv.y, xv.y, acc[1][1]);
    acc[1][2] = fmaf(cv.y, xv.z, acc[1][2]);
    acc[1][3] = fmaf(cv.y, xv.w, acc[1][3]);
    acc[2][0] = fmaf(cv.z, xv.x, acc[2][0]);
    acc[2][1] = fmaf(cv.z, xv.y, acc[2][1]);
    acc[2][2] = fmaf(cv.z, xv.z, acc[2][2]);
    acc[2][3] = fmaf(cv.z, xv.w, acc[2][3]);
    acc[3][0] = fmaf(cv.w, xv.x, acc[3][0]);
    acc[3][1] = fmaf(cv.w, xv.y, acc[3][1]);
    acc[3][2] = fmaf(cv.w, xv.z, acc[3][2]);
    acc[3][3] = fmaf(cv.w, xv.w, acc[3][3]);
  }

  // logits and per-wave (4-p) max per pixel
  float lg[4][4], mq[4];
#pragma unroll
  for (int q = 0; q < 4; ++q) mq[q] = -3.4e38f;
#pragma unroll
  for (int j = 0; j < 4; ++j) {
    float cs = csq[p0 + j], rb = rbeta[p0 + j];
#pragma unroll
    for (int q = 0; q < 4; ++q) {
      float l = fminf(2.f * acc[j][q] - xsq[q] - cs, 0.f) * rb;
      lg[j][q] = l;
      mq[q] = fmaxf(mq[q], l);
    }
  }
#pragma unroll
  for (int q = 0; q < 4; ++q) redA[wv][lane][q] = mq[q];
  __syncthreads();
#pragma unroll
  for (int q = 0; q < 4; ++q) {
    float m = redA[0][lane][q];
#pragma unroll
    for (int k = 1; k < 8; ++k) m = fmaxf(m, redA[k][lane][q]);
    mq[q] = m;
  }
  float sq[4] = {0.f, 0.f, 0.f, 0.f};
#pragma unroll
  for (int j = 0; j < 4; ++j)
#pragma unroll
    for (int q = 0; q < 4; ++q) {
      float e = __expf(lg[j][q] - mq[q]);
      lg[j][q] = e;
      sq[q] += e;
    }
#pragma unroll
  for (int q = 0; q < 4; ++q) redB[wv][lane][q] = sq[q];
  __syncthreads();
#pragma unroll
  for (int q = 0; q < 4; ++q) {
    float s = redB[0][lane][q];
#pragma unroll
    for (int k = 1; k < 8; ++k) s += redB[k][lane][q];
    sq[q] = 1.f / s;
  }

  float* ao = assign_out + ((size_t)b * PP + p0) * NN + n0 + (lane << 2);
#pragma unroll
  for (int j = 0; j < 4; ++j) {
    float a0 = lg[j][0] * sq[0], a1 = lg[j][1] * sq[1];
    float a2 = lg[j][2] * sq[2], a3 = lg[j][3] * sq[3];
    *(float4*)&ao[(size_t)j * NN] = make_float4(a0, a1, a2, a3);
    float ssum = (a0 + a1) + (a2 + a3);
#pragma unroll
    for (int off = 32; off; off >>= 1) ssum += __shfl_down(ssum, off);
    if (lane == 0) atomicAdd(&sum_ass[b * PP + p0 + j], ssum);
  }
}

// ---------------------------------------------------------------------------
// qx tiled GEMM: qx[b][p][c] = sum_k assign[b][p][k] * x[b][c][k]
// grid (32 = 8 kchunks x 4 ctiles, 16 b), block 256.
// ---------------------------------------------------------------------------
__global__ __launch_bounds__(256) void qx_kernel(
    const float* __restrict__ x, const float* __restrict__ assign,
    float* __restrict__ qx) {
  __shared__ float xs[64][132];   // 33 KB
  __shared__ float as[64][36];    // 9.2 KB

  int tid = threadIdx.x;
  int b = blockIdx.y;
  int kc = blockIdx.x >> 2;       // 0..7
  int ct = blockIdx.x & 3;        // 0..3
  const float* xb = x + ((size_t)b * CC + ct * 128) * NN + kc * 512;
  const float* ab = assign + (size_t)b * PP * NN + kc * 512;

  int cq = (tid & 31) << 2;       // compute c offset 0..124
  int pq = (tid >> 5) << 2;       // compute p offset 0..28
  int xk = tid & 63;              // staging: lane = k (coalesced global)
  int xc = tid >> 6;              // staging c-quad base 0..3
  int ap_ = tid >> 3;             // assign staging p 0..31
  int ak = (tid & 7) << 2;        // assign staging k quad 0..28

  float acc[16];
#pragma unroll
  for (int i = 0; i < 16; ++i) acc[i] = 0.f;

  for (int ks = 0; ks < 512; ks += 64) {
    float xv[8][4];
#pragma unroll
    for (int pass = 0; pass < 8; ++pass) {
      int c4 = (xc + pass * 4) << 2;
#pragma unroll
      for (int i = 0; i < 4; ++i)
        xv[pass][i] = xb[(size_t)(c4 + i) * NN + ks + xk];
    }
    float4 a0 = *(const float4*)&ab[(size_t)ap_ * NN + ks + ak];
    float4 a1 = *(const float4*)&ab[(size_t)ap_ * NN + ks + ak + 32];
    __syncthreads();
#pragma unroll
    for (int pass = 0; pass < 8; ++pass) {
      int c4 = (xc + pass * 4) << 2;
      *(float4*)&xs[xk][c4] =
          make_float4(xv[pass][0], xv[pass][1], xv[pass][2], xv[pass][3]);
    }
    as[ak + 0][ap_] = a0.x; as[ak + 1][ap_] = a0.y;
    as[ak + 2][ap_] = a0.z; as[ak + 3][ap_] = a0.w;
    as[ak + 32][ap_] = a1.x; as[ak + 33][ap_] = a1.y;
    as[ak + 34][ap_] = a1.z; as[ak + 35][ap_] = a1.w;
    __syncthreads();
#pragma unroll 8
    for (int k = 0; k < 64; ++k) {
      float4 xvv = *(const float4*)&xs[k][cq];
      float4 avv = *(const float4*)&as[k][pq];  // broadcast
      acc[0]  = fmaf(avv.x, xvv.x, acc[0]);
      acc[1]  = fmaf(avv.x, xvv.y, acc[1]);
      acc[2]  = fmaf(avv.x, xvv.z, acc[2]);
      acc[3]  = fmaf(avv.x, xvv.w, acc[3]);
      acc[4]  = fmaf(avv.y, xvv.x, acc[4]);
      acc[5]  = fmaf(avv.y, xvv.y, acc[5]);
      acc[6]  = fmaf(avv.y, xvv.z, acc[6]);
      acc[7]  = fmaf(avv.y, xvv.w, acc[7]);
      acc[8]  = fmaf(avv.z, xvv.x, acc[8]);
      acc[9]  = fmaf(avv.z, xvv.y, acc[9]);
      acc[10] = fmaf(avv.z, xvv.z, acc[10]);
      acc[11] = fmaf(avv.z, xvv.w, acc[11]);
      acc[12] = fmaf(avv.w, xvv.x, acc[12]);
      acc[13] = fmaf(avv.w, xvv.y, acc[13]);
      acc[14] = fmaf(avv.w, xvv.z, acc[14]);
      acc[15] = fmaf(avv.w, xvv.w, acc[15]);
    }
  }

#pragma unroll
  for (int i = 0; i < 4; ++i) {
    float* q = qx + ((size_t)b * PP + pq + i) * CC + ct * 128 + cq;
#pragma unroll
    for (int j = 0; j < 4; ++j) atomicAdd(&q[j], acc[i * 4 + j]);
  }
}

// ---------------------------------------------------------------------------
// finalize: out = (qx/max(sum_ass,1e-5) - centers)/sigma ; L2-normalize;
// write transposed out_t[b][c][p]. block per (b,p), 256 threads, 2 c each.
// ---------------------------------------------------------------------------
__global__ __launch_bounds__(256) void finalize_kernel(
    const float* __restrict__ qx, const float* __restrict__ w,
    const float* __restrict__ beta, const float* __restrict__ sum_ass,
    float* __restrict__ out_t) {
  int b = blockIdx.x >> 5;
  int p = blockIdx.x & 31;
  int tid = threadIdx.x;
  int wave = tid >> 6, lane = tid & 63;

  float inv_sa = 1.f / fmaxf(sum_ass[b * PP + p], 1e-5f);
  float rsig = rsqrtf(0.5f * beta[p]);

  int c0 = tid, c1 = tid + 256;
  const float* qrow = qx + ((size_t)b * PP + p) * CC;
  const float* wrow = w + (size_t)p * CC;
  float t0 = (qrow[c0] * inv_sa - wrow[c0]) * rsig;
  float t1 = (qrow[c1] * inv_sa - wrow[c1]) * rsig;

  float nr = t0 * t0 + t1 * t1;
#pragma unroll
  for (int off = 32; off; off >>= 1) nr += __shfl_down(nr, off);
  __shared__ float red[4];
  if (lane == 0) red[wave] = nr;
  __syncthreads();
  float norm2 = red[0] + red[1] + red[2] + red[3];
  float scale = 1.f / fmaxf(sqrtf(norm2), 1e-12f);

  float* ob = out_t + (size_t)b * CC * PP + p;
  ob[(size_t)c0 * PP] = t0 * scale;
  ob[(size_t)c1 * PP] = t1 * scale;
}

// ---------------------------------------------------------------------------
extern "C" void kernel_launch(void* const* d_in, const int* in_sizes, int n_in,
                              void* d_out, int out_size, void* d_ws,
                              size_t ws_size, hipStream_t stream) {
  const float* x = (const float*)d_in[0];   // [B,C,H,W]
  const float* w = (const float*)d_in[1];   // [P,C,1,1]
  const float* sf = (const float*)d_in[2];  // [P]

  float* out_t = (float*)d_out;                  // [B,C,P]
  float* assign = out_t + (size_t)BB * CC * PP;  // [B,P,N]

  float* ws = (float*)d_ws;
  float* beta = ws;           // 32
  float* rbeta = ws + 32;     // 32
  float* csq = ws + 64;       // 32
  float* sum_ass = ws + 96;   // 512
  float* qx = ws + 608;       // B*P*C = 262144

  // zero sum_ass + qx (contiguous) for atomic accumulation
  hipMemsetAsync(sum_ass, 0, (512 + (size_t)BB * PP * CC) * sizeof(float),
                 stream);
  prep_kernel<<<PP, 64, 0, stream>>>(w, sf, beta, rbeta, csq);
  assign_kernel<<<BB * 16, 512, 0, stream>>>(x, w, rbeta, csq, assign,
                                             sum_ass);
  qx_kernel<<<dim3(32, BB), 256, 0, stream>>>(x, assign, qx);
  finalize_kernel<<<BB * PP, 256, 0, stream>>>(qx, w, beta, sum_ass, out_t);
}

// Round 4
// 112.422 us; speedup vs baseline: 1.1170x; 1.1170x over previous
//
#include <hip/hip_runtime.h>

constexpr int BB = 16;     // batch
constexpr int CC = 512;    // channels
constexpr int PP = 32;     // clusters
constexpr int NN = 4096;   // H*W
constexpr int TN = 128;    // assign n-tile per block

// ---------------------------------------------------------------------------
// prep: beta = sigmoid(sf), rbeta = 1/beta, csq[p] = |centers_p|^2
// ---------------------------------------------------------------------------
__global__ __launch_bounds__(64) void prep_kernel(
    const float* __restrict__ w, const float* __restrict__ sf,
    float* __restrict__ beta, float* __restrict__ rbeta,
    float* __restrict__ csq) {
  int p = blockIdx.x;
  int t = threadIdx.x;
  float s = 0.f;
  for (int i = t; i < CC; i += 64) {
    float v = w[p * CC + i];
    s = fmaf(v, v, s);
  }
#pragma unroll
  for (int off = 32; off; off >>= 1) s += __shfl_down(s, off);
  if (t == 0) {
    csq[p] = s;
    float e = __expf(-sf[p]);
    rbeta[p] = 1.f + e;            // 1/beta
    beta[p] = 1.f / (1.f + e);     // beta
  }
}

// ---------------------------------------------------------------------------
// assign as LDS-tiled GEMM (qx-style): cx[p][n] = sum_c cent[c][p]*x[c][n].
// grid 512 (16 b x 32 n-tiles of 128), block 256.
// Output tile 32p x 128n per block; K=512 in 8 chunks of 64.
// xsq accumulated from staging registers, reduced via LDS.
// Softmax epilogue via [128][37] transpose aliased onto dead x-tile.
// Fused sum_ass atomics. Writes assign [B,P,N].
// ---------------------------------------------------------------------------
__global__ __launch_bounds__(256) void assign_kernel(
    const float* __restrict__ x, const float* __restrict__ w,
    const float* __restrict__ rbeta, const float* __restrict__ csq,
    float* __restrict__ assign_out, float* __restrict__ sum_ass) {
  __shared__ float xs[64][132];    // x chunk [c][n] 33.8 KB (reused as lgs)
  __shared__ float cs[64][36];     // centers chunk [c][p] 9.2 KB
  __shared__ float xsq_p[8][TN];   // xsq partials per c-group, 4 KB

  int tid = threadIdx.x;
  int b = blockIdx.x >> 5;
  int n0 = (blockIdx.x & 31) * TN;

  int sc = tid >> 5;            // x staging row group 0..7
  int sn = (tid & 31) << 2;     // x staging n-quad (== compute n-quad)
  int sp = tid >> 3;            // w staging p 0..31
  int sk = (tid & 7) << 2;      // w staging c-quad 0..28

  int nq = (tid & 31) << 2;     // compute n offset 0..124
  int pq = (tid >> 5) << 2;     // compute p offset 0..28

  const float* xb = x + (size_t)b * CC * NN + n0;

  float acc[16];
#pragma unroll
  for (int i = 0; i < 16; ++i) acc[i] = 0.f;
  float xq0 = 0.f, xq1 = 0.f, xq2 = 0.f, xq3 = 0.f;

  for (int c0 = 0; c0 < CC; c0 += 64) {
    float4 xr[8];
#pragma unroll
    for (int ps = 0; ps < 8; ++ps)
      xr[ps] = *(const float4*)&xb[(size_t)(c0 + sc + ps * 8) * NN + sn];
    float4 w0 = *(const float4*)&w[(size_t)sp * CC + c0 + sk];
    float4 w1 = *(const float4*)&w[(size_t)sp * CC + c0 + sk + 32];
    __syncthreads();  // previous chunk's readers done
#pragma unroll
    for (int ps = 0; ps < 8; ++ps) {
      *(float4*)&xs[sc + ps * 8][sn] = xr[ps];
      xq0 = fmaf(xr[ps].x, xr[ps].x, xq0);
      xq1 = fmaf(xr[ps].y, xr[ps].y, xq1);
      xq2 = fmaf(xr[ps].z, xr[ps].z, xq2);
      xq3 = fmaf(xr[ps].w, xr[ps].w, xq3);
    }
    cs[sk + 0][sp] = w0.x; cs[sk + 1][sp] = w0.y;
    cs[sk + 2][sp] = w0.z; cs[sk + 3][sp] = w0.w;
    cs[sk + 32][sp] = w1.x; cs[sk + 33][sp] = w1.y;
    cs[sk + 34][sp] = w1.z; cs[sk + 35][sp] = w1.w;
    __syncthreads();
#pragma unroll 8
    for (int k = 0; k < 64; ++k) {
      float4 xv = *(const float4*)&xs[k][nq];
      float4 av = *(const float4*)&cs[k][pq];  // broadcast
      acc[0]  = fmaf(av.x, xv.x, acc[0]);
      acc[1]  = fmaf(av.x, xv.y, acc[1]);
      acc[2]  = fmaf(av.x, xv.z, acc[2]);
      acc[3]  = fmaf(av.x, xv.w, acc[3]);
      acc[4]  = fmaf(av.y, xv.x, acc[4]);
      acc[5]  = fmaf(av.y, xv.y, acc[5]);
      acc[6]  = fmaf(av.y, xv.z, acc[6]);
      acc[7]  = fmaf(av.y, xv.w, acc[7]);
      acc[8]  = fmaf(av.z, xv.x, acc[8]);
      acc[9]  = fmaf(av.z, xv.y, acc[9]);
      acc[10] = fmaf(av.z, xv.z, acc[10]);
      acc[11] = fmaf(av.z, xv.w, acc[11]);
      acc[12] = fmaf(av.w, xv.x, acc[12]);
      acc[13] = fmaf(av.w, xv.y, acc[13]);
      acc[14] = fmaf(av.w, xv.z, acc[14]);
      acc[15] = fmaf(av.w, xv.w, acc[15]);
    }
  }

  // publish xsq partials (own buffer; consumed after barrier)
  *(float4*)&xsq_p[sc][sn] = make_float4(xq0, xq1, xq2, xq3);
  __syncthreads();  // xs free for aliasing AND xsq_p ready

  float xs0 = 0.f, xs1 = 0.f, xs2 = 0.f, xs3 = 0.f;
#pragma unroll
  for (int g = 0; g < 8; ++g) {
    float4 v = *(const float4*)&xsq_p[g][nq];
    xs0 += v.x; xs1 += v.y; xs2 += v.z; xs3 += v.w;
  }

  // logits -> transposed LDS lgs[n][p] (stride 37: conflict-light scalars)
  float* lgs = &xs[0][0];  // [128][37] = 4736 floats < 8448
#pragma unroll
  for (int j = 0; j < 4; ++j) {
    float csj = csq[pq + j], rbj = rbeta[pq + j];
    lgs[(nq + 0) * 37 + pq + j] = fminf(2.f * acc[j * 4 + 0] - xs0 - csj, 0.f) * rbj;
    lgs[(nq + 1) * 37 + pq + j] = fminf(2.f * acc[j * 4 + 1] - xs1 - csj, 0.f) * rbj;
    lgs[(nq + 2) * 37 + pq + j] = fminf(2.f * acc[j * 4 + 2] - xs2 - csj, 0.f) * rbj;
    lgs[(nq + 3) * 37 + pq + j] = fminf(2.f * acc[j * 4 + 3] - xs3 - csj, 0.f) * rbj;
  }
  __syncthreads();

  // softmax over p per pixel: threads 0..127, one n each
  if (tid < TN) {
    float v[PP];
    float m = -3.4e38f;
#pragma unroll
    for (int p = 0; p < PP; ++p) {
      v[p] = lgs[tid * 37 + p];
      m = fmaxf(m, v[p]);
    }
    float s = 0.f;
#pragma unroll
    for (int p = 0; p < PP; ++p) {
      v[p] = __expf(v[p] - m);
      s += v[p];
    }
    float inv = 1.f / s;
#pragma unroll
    for (int p = 0; p < PP; ++p) lgs[tid * 37 + p] = v[p] * inv;
  }
  __syncthreads();

  // store (transposed gather) + fused sum_ass
#pragma unroll
  for (int rep = 0; rep < 4; ++rep) {
    int idx = tid + rep * 256;       // 0..1023
    int p = idx >> 5;                // 0..31
    int nf = (idx & 31) << 2;        // 0..124
    float a0 = lgs[(nf + 0) * 37 + p];
    float a1 = lgs[(nf + 1) * 37 + p];
    float a2 = lgs[(nf + 2) * 37 + p];
    float a3 = lgs[(nf + 3) * 37 + p];
    *(float4*)&assign_out[((size_t)b * PP + p) * NN + n0 + nf] =
        make_float4(a0, a1, a2, a3);
    float s = (a0 + a1) + (a2 + a3);
#pragma unroll
    for (int off = 16; off; off >>= 1) s += __shfl_down(s, off, 32);
    if ((tid & 31) == 0) atomicAdd(&sum_ass[b * PP + p], s);
  }
}

// ---------------------------------------------------------------------------
// qx tiled GEMM: qx[b][p][c] = sum_k assign[b][p][k] * x[b][c][k]
// grid (32 = 8 kchunks x 4 ctiles, 16 b), block 256.
// ---------------------------------------------------------------------------
__global__ __launch_bounds__(256) void qx_kernel(
    const float* __restrict__ x, const float* __restrict__ assign,
    float* __restrict__ qx) {
  __shared__ float xs[64][132];   // 33 KB
  __shared__ float as[64][36];    // 9.2 KB

  int tid = threadIdx.x;
  int b = blockIdx.y;
  int kc = blockIdx.x >> 2;       // 0..7
  int ct = blockIdx.x & 3;        // 0..3
  const float* xb = x + ((size_t)b * CC + ct * 128) * NN + kc * 512;
  const float* ab = assign + (size_t)b * PP * NN + kc * 512;

  int cq = (tid & 31) << 2;       // compute c offset 0..124
  int pq = (tid >> 5) << 2;       // compute p offset 0..28
  int xk = tid & 63;              // staging: lane = k (coalesced global)
  int xc = tid >> 6;              // staging c-quad base 0..3
  int ap_ = tid >> 3;             // assign staging p 0..31
  int ak = (tid & 7) << 2;        // assign staging k quad 0..28

  float acc[16];
#pragma unroll
  for (int i = 0; i < 16; ++i) acc[i] = 0.f;

  for (int ks = 0; ks < 512; ks += 64) {
    float xv[8][4];
#pragma unroll
    for (int pass = 0; pass < 8; ++pass) {
      int c4 = (xc + pass * 4) << 2;
#pragma unroll
      for (int i = 0; i < 4; ++i)
        xv[pass][i] = xb[(size_t)(c4 + i) * NN + ks + xk];
    }
    float4 a0 = *(const float4*)&ab[(size_t)ap_ * NN + ks + ak];
    float4 a1 = *(const float4*)&ab[(size_t)ap_ * NN + ks + ak + 32];
    __syncthreads();
#pragma unroll
    for (int pass = 0; pass < 8; ++pass) {
      int c4 = (xc + pass * 4) << 2;
      *(float4*)&xs[xk][c4] =
          make_float4(xv[pass][0], xv[pass][1], xv[pass][2], xv[pass][3]);
    }
    as[ak + 0][ap_] = a0.x; as[ak + 1][ap_] = a0.y;
    as[ak + 2][ap_] = a0.z; as[ak + 3][ap_] = a0.w;
    as[ak + 32][ap_] = a1.x; as[ak + 33][ap_] = a1.y;
    as[ak + 34][ap_] = a1.z; as[ak + 35][ap_] = a1.w;
    __syncthreads();
#pragma unroll 8
    for (int k = 0; k < 64; ++k) {
      float4 xvv = *(const float4*)&xs[k][cq];
      float4 avv = *(const float4*)&as[k][pq];  // broadcast
      acc[0]  = fmaf(avv.x, xvv.x, acc[0]);
      acc[1]  = fmaf(avv.x, xvv.y, acc[1]);
      acc[2]  = fmaf(avv.x, xvv.z, acc[2]);
      acc[3]  = fmaf(avv.x, xvv.w, acc[3]);
      acc[4]  = fmaf(avv.y, xvv.x, acc[4]);
      acc[5]  = fmaf(avv.y, xvv.y, acc[5]);
      acc[6]  = fmaf(avv.y, xvv.z, acc[6]);
      acc[7]  = fmaf(avv.y, xvv.w, acc[7]);
      acc[8]  = fmaf(avv.z, xvv.x, acc[8]);
      acc[9]  = fmaf(avv.z, xvv.y, acc[9]);
      acc[10] = fmaf(avv.z, xvv.z, acc[10]);
      acc[11] = fmaf(avv.z, xvv.w, acc[11]);
      acc[12] = fmaf(avv.w, xvv.x, acc[12]);
      acc[13] = fmaf(avv.w, xvv.y, acc[13]);
      acc[14] = fmaf(avv.w, xvv.z, acc[14]);
      acc[15] = fmaf(avv.w, xvv.w, acc[15]);
    }
  }

#pragma unroll
  for (int i = 0; i < 4; ++i) {
    float* q = qx + ((size_t)b * PP + pq + i) * CC + ct * 128 + cq;
#pragma unroll
    for (int j = 0; j < 4; ++j) atomicAdd(&q[j], acc[i * 4 + j]);
  }
}

// ---------------------------------------------------------------------------
// finalize: out = (qx/max(sum_ass,1e-5) - centers)/sigma ; L2-normalize;
// write transposed out_t[b][c][p]. block per (b,p), 256 threads, 2 c each.
// ---------------------------------------------------------------------------
__global__ __launch_bounds__(256) void finalize_kernel(
    const float* __restrict__ qx, const float* __restrict__ w,
    const float* __restrict__ beta, const float* __restrict__ sum_ass,
    float* __restrict__ out_t) {
  int b = blockIdx.x >> 5;
  int p = blockIdx.x & 31;
  int tid = threadIdx.x;
  int wave = tid >> 6, lane = tid & 63;

  float inv_sa = 1.f / fmaxf(sum_ass[b * PP + p], 1e-5f);
  float rsig = rsqrtf(0.5f * beta[p]);

  int c0 = tid, c1 = tid + 256;
  const float* qrow = qx + ((size_t)b * PP + p) * CC;
  const float* wrow = w + (size_t)p * CC;
  float t0 = (qrow[c0] * inv_sa - wrow[c0]) * rsig;
  float t1 = (qrow[c1] * inv_sa - wrow[c1]) * rsig;

  float nr = t0 * t0 + t1 * t1;
#pragma unroll
  for (int off = 32; off; off >>= 1) nr += __shfl_down(nr, off);
  __shared__ float red[4];
  if (lane == 0) red[wave] = nr;
  __syncthreads();
  float norm2 = red[0] + red[1] + red[2] + red[3];
  float scale = 1.f / fmaxf(sqrtf(norm2), 1e-12f);

  float* ob = out_t + (size_t)b * CC * PP + p;
  ob[(size_t)c0 * PP] = t0 * scale;
  ob[(size_t)c1 * PP] = t1 * scale;
}

// ---------------------------------------------------------------------------
extern "C" void kernel_launch(void* const* d_in, const int* in_sizes, int n_in,
                              void* d_out, int out_size, void* d_ws,
                              size_t ws_size, hipStream_t stream) {
  const float* x = (const float*)d_in[0];   // [B,C,H,W]
  const float* w = (const float*)d_in[1];   // [P,C,1,1]
  const float* sf = (const float*)d_in[2];  // [P]

  float* out_t = (float*)d_out;                  // [B,C,P]
  float* assign = out_t + (size_t)BB * CC * PP;  // [B,P,N]

  float* ws = (float*)d_ws;
  float* beta = ws;           // 32
  float* rbeta = ws + 32;     // 32
  float* csq = ws + 64;       // 32
  float* sum_ass = ws + 96;   // 512
  float* qx = ws + 608;       // B*P*C = 262144

  // zero sum_ass + qx (contiguous) for atomic accumulation
  hipMemsetAsync(sum_ass, 0, (512 + (size_t)BB * PP * CC) * sizeof(float),
                 stream);
  prep_kernel<<<PP, 64, 0, stream>>>(w, sf, beta, rbeta, csq);
  assign_kernel<<<BB * 32, 256, 0, stream>>>(x, w, rbeta, csq, assign,
                                             sum_ass);
  qx_kernel<<<dim3(32, BB), 256, 0, stream>>>(x, assign, qx);
  finalize_kernel<<<BB * PP, 256, 0, stream>>>(qx, w, beta, sum_ass, out_t);
}

// Round 5
// 101.109 us; speedup vs baseline: 1.2420x; 1.1119x over previous
//
#include <hip/hip_runtime.h>

constexpr int BB = 16;     // batch
constexpr int CC = 512;    // channels
constexpr int PP = 32;     // clusters
constexpr int NN = 4096;   // H*W
constexpr int TN = 128;    // assign n-tile per block

// ---------------------------------------------------------------------------
// prep: beta = sigmoid(sf), rbeta = 1/beta, csq[p] = |centers_p|^2.
// Also zeroes sum_ass (runs before assign's atomics; stream-ordered).
// ---------------------------------------------------------------------------
__global__ __launch_bounds__(64) void prep_kernel(
    const float* __restrict__ w, const float* __restrict__ sf,
    float* __restrict__ beta, float* __restrict__ rbeta,
    float* __restrict__ csq, float* __restrict__ sum_ass) {
  int p = blockIdx.x;
  int t = threadIdx.x;
  if (t < 16) sum_ass[p * 16 + t] = 0.f;
  float s = 0.f;
  for (int i = t; i < CC; i += 64) {
    float v = w[p * CC + i];
    s = fmaf(v, v, s);
  }
#pragma unroll
  for (int off = 32; off; off >>= 1) s += __shfl_down(s, off);
  if (t == 0) {
    csq[p] = s;
    float e = __expf(-sf[p]);
    rbeta[p] = 1.f + e;            // 1/beta
    beta[p] = 1.f / (1.f + e);     // beta
  }
}

// ---------------------------------------------------------------------------
// assign as LDS-tiled GEMM, software-pipelined: cx[p][n] = sum_c cent[c][p]*x[c][n].
// grid 512 (16 b x 32 n-tiles of 128), block 256.
// Chunk k+1's global loads issue BEFORE the inner loop over chunk k.
// xsq accumulated from staging registers. Softmax epilogue via [128][37]
// transpose aliased onto dead x-tile. Fused sum_ass atomics.
// ---------------------------------------------------------------------------
__global__ __launch_bounds__(256) void assign_kernel(
    const float* __restrict__ x, const float* __restrict__ w,
    const float* __restrict__ rbeta, const float* __restrict__ csq,
    float* __restrict__ assign_out, float* __restrict__ sum_ass) {
  __shared__ float xs[64][132];    // x chunk [c][n] 33.8 KB (reused as lgs)
  __shared__ float cs[64][36];     // centers chunk [c][p] 9.2 KB
  __shared__ float xsq_p[8][TN];   // xsq partials per c-group, 4 KB

  int tid = threadIdx.x;
  int b = blockIdx.x >> 5;
  int n0 = (blockIdx.x & 31) * TN;

  int sc = tid >> 5;            // x staging row group 0..7
  int sn = (tid & 31) << 2;     // x staging n-quad
  int sp = tid >> 3;            // w staging p 0..31
  int sk = (tid & 7) << 2;      // w staging c-quad 0..28

  int nq = (tid & 31) << 2;     // compute n offset 0..124
  int pq = (tid >> 5) << 2;     // compute p offset 0..28

  const float* xb = x + (size_t)b * CC * NN + n0;

  float acc[16];
#pragma unroll
  for (int i = 0; i < 16; ++i) acc[i] = 0.f;
  float xq0 = 0.f, xq1 = 0.f, xq2 = 0.f, xq3 = 0.f;

  float4 xr[8], w0v, w1v;
  // prologue: load + stage chunk 0
#pragma unroll
  for (int ps = 0; ps < 8; ++ps)
    xr[ps] = *(const float4*)&xb[(size_t)(sc + ps * 8) * NN + sn];
  w0v = *(const float4*)&w[(size_t)sp * CC + sk];
  w1v = *(const float4*)&w[(size_t)sp * CC + sk + 32];
#pragma unroll
  for (int ps = 0; ps < 8; ++ps) {
    *(float4*)&xs[sc + ps * 8][sn] = xr[ps];
    xq0 = fmaf(xr[ps].x, xr[ps].x, xq0);
    xq1 = fmaf(xr[ps].y, xr[ps].y, xq1);
    xq2 = fmaf(xr[ps].z, xr[ps].z, xq2);
    xq3 = fmaf(xr[ps].w, xr[ps].w, xq3);
  }
  cs[sk + 0][sp] = w0v.x; cs[sk + 1][sp] = w0v.y;
  cs[sk + 2][sp] = w0v.z; cs[sk + 3][sp] = w0v.w;
  cs[sk + 32][sp] = w1v.x; cs[sk + 33][sp] = w1v.y;
  cs[sk + 34][sp] = w1v.z; cs[sk + 35][sp] = w1v.w;
  __syncthreads();

  for (int c0 = 0; c0 < CC; c0 += 64) {
    bool more = (c0 + 64 < CC);
    if (more) {  // issue next chunk's loads early; held in regs during inner
#pragma unroll
      for (int ps = 0; ps < 8; ++ps)
        xr[ps] = *(const float4*)&xb[(size_t)(c0 + 64 + sc + ps * 8) * NN + sn];
      w0v = *(const float4*)&w[(size_t)sp * CC + c0 + 64 + sk];
      w1v = *(const float4*)&w[(size_t)sp * CC + c0 + 64 + sk + 32];
    }
#pragma unroll 8
    for (int k = 0; k < 64; ++k) {
      float4 xv = *(const float4*)&xs[k][nq];
      float4 av = *(const float4*)&cs[k][pq];  // broadcast
      acc[0]  = fmaf(av.x, xv.x, acc[0]);
      acc[1]  = fmaf(av.x, xv.y, acc[1]);
      acc[2]  = fmaf(av.x, xv.z, acc[2]);
      acc[3]  = fmaf(av.x, xv.w, acc[3]);
      acc[4]  = fmaf(av.y, xv.x, acc[4]);
      acc[5]  = fmaf(av.y, xv.y, acc[5]);
      acc[6]  = fmaf(av.y, xv.z, acc[6]);
      acc[7]  = fmaf(av.y, xv.w, acc[7]);
      acc[8]  = fmaf(av.z, xv.x, acc[8]);
      acc[9]  = fmaf(av.z, xv.y, acc[9]);
      acc[10] = fmaf(av.z, xv.z, acc[10]);
      acc[11] = fmaf(av.z, xv.w, acc[11]);
      acc[12] = fmaf(av.w, xv.x, acc[12]);
      acc[13] = fmaf(av.w, xv.y, acc[13]);
      acc[14] = fmaf(av.w, xv.z, acc[14]);
      acc[15] = fmaf(av.w, xv.w, acc[15]);
    }
    if (more) {
      __syncthreads();  // inner done reading old chunk
#pragma unroll
      for (int ps = 0; ps < 8; ++ps) {
        *(float4*)&xs[sc + ps * 8][sn] = xr[ps];
        xq0 = fmaf(xr[ps].x, xr[ps].x, xq0);
        xq1 = fmaf(xr[ps].y, xr[ps].y, xq1);
        xq2 = fmaf(xr[ps].z, xr[ps].z, xq2);
        xq3 = fmaf(xr[ps].w, xr[ps].w, xq3);
      }
      cs[sk + 0][sp] = w0v.x; cs[sk + 1][sp] = w0v.y;
      cs[sk + 2][sp] = w0v.z; cs[sk + 3][sp] = w0v.w;
      cs[sk + 32][sp] = w1v.x; cs[sk + 33][sp] = w1v.y;
      cs[sk + 34][sp] = w1v.z; cs[sk + 35][sp] = w1v.w;
      __syncthreads();
    }
  }

  // publish xsq partials
  *(float4*)&xsq_p[sc][sn] = make_float4(xq0, xq1, xq2, xq3);
  __syncthreads();  // xs free for aliasing AND xsq_p ready

  float xs0 = 0.f, xs1 = 0.f, xs2 = 0.f, xs3 = 0.f;
#pragma unroll
  for (int g = 0; g < 8; ++g) {
    float4 v = *(const float4*)&xsq_p[g][nq];
    xs0 += v.x; xs1 += v.y; xs2 += v.z; xs3 += v.w;
  }

  // logits -> transposed LDS lgs[n][p] (stride 37)
  float* lgs = &xs[0][0];  // [128][37] = 4736 floats < 8448
#pragma unroll
  for (int j = 0; j < 4; ++j) {
    float csj = csq[pq + j], rbj = rbeta[pq + j];
    lgs[(nq + 0) * 37 + pq + j] = fminf(2.f * acc[j * 4 + 0] - xs0 - csj, 0.f) * rbj;
    lgs[(nq + 1) * 37 + pq + j] = fminf(2.f * acc[j * 4 + 1] - xs1 - csj, 0.f) * rbj;
    lgs[(nq + 2) * 37 + pq + j] = fminf(2.f * acc[j * 4 + 2] - xs2 - csj, 0.f) * rbj;
    lgs[(nq + 3) * 37 + pq + j] = fminf(2.f * acc[j * 4 + 3] - xs3 - csj, 0.f) * rbj;
  }
  __syncthreads();

  // softmax over p per pixel: threads 0..127, one n each
  if (tid < TN) {
    float v[PP];
    float m = -3.4e38f;
#pragma unroll
    for (int p = 0; p < PP; ++p) {
      v[p] = lgs[tid * 37 + p];
      m = fmaxf(m, v[p]);
    }
    float s = 0.f;
#pragma unroll
    for (int p = 0; p < PP; ++p) {
      v[p] = __expf(v[p] - m);
      s += v[p];
    }
    float inv = 1.f / s;
#pragma unroll
    for (int p = 0; p < PP; ++p) lgs[tid * 37 + p] = v[p] * inv;
  }
  __syncthreads();

  // store (transposed gather) + fused sum_ass
#pragma unroll
  for (int rep = 0; rep < 4; ++rep) {
    int idx = tid + rep * 256;       // 0..1023
    int p = idx >> 5;                // 0..31
    int nf = (idx & 31) << 2;        // 0..124
    float a0 = lgs[(nf + 0) * 37 + p];
    float a1 = lgs[(nf + 1) * 37 + p];
    float a2 = lgs[(nf + 2) * 37 + p];
    float a3 = lgs[(nf + 3) * 37 + p];
    *(float4*)&assign_out[((size_t)b * PP + p) * NN + n0 + nf] =
        make_float4(a0, a1, a2, a3);
    float s = (a0 + a1) + (a2 + a3);
#pragma unroll
    for (int off = 16; off; off >>= 1) s += __shfl_down(s, off, 32);
    if ((tid & 31) == 0) atomicAdd(&sum_ass[b * PP + p], s);
  }
}

// ---------------------------------------------------------------------------
// qx tiled GEMM, software-pipelined, non-atomic k-split partial stores:
// qx_part[kc][b][p][c] = sum_{k in chunk kc} assign[b][p][k] * x[b][c][k]
// grid (32 = 8 kchunks x 4 ctiles, 16 b), block 256.
// ---------------------------------------------------------------------------
__global__ __launch_bounds__(256) void qx_kernel(
    const float* __restrict__ x, const float* __restrict__ assign,
    float* __restrict__ qx_part) {
  __shared__ float xs[64][132];   // 33 KB
  __shared__ float as[64][36];    // 9.2 KB

  int tid = threadIdx.x;
  int b = blockIdx.y;
  int kc = blockIdx.x >> 2;       // 0..7
  int ct = blockIdx.x & 3;        // 0..3
  const float* xb = x + ((size_t)b * CC + ct * 128) * NN + kc * 512;
  const float* ab = assign + (size_t)b * PP * NN + kc * 512;

  int cq = (tid & 31) << 2;       // compute c offset 0..124
  int pq = (tid >> 5) << 2;       // compute p offset 0..28
  int xk = tid & 63;              // staging: lane = k (coalesced global)
  int xc = tid >> 6;              // staging c-quad base 0..3
  int ap_ = tid >> 3;             // assign staging p 0..31
  int ak = (tid & 7) << 2;        // assign staging k quad 0..28

  float acc[16];
#pragma unroll
  for (int i = 0; i < 16; ++i) acc[i] = 0.f;

  float xv[8][4];
  float4 a0v, a1v;
  // prologue: load + stage chunk 0
#pragma unroll
  for (int pass = 0; pass < 8; ++pass) {
    int c4 = (xc + pass * 4) << 2;
#pragma unroll
    for (int i = 0; i < 4; ++i)
      xv[pass][i] = xb[(size_t)(c4 + i) * NN + xk];
  }
  a0v = *(const float4*)&ab[(size_t)ap_ * NN + ak];
  a1v = *(const float4*)&ab[(size_t)ap_ * NN + ak + 32];
#pragma unroll
  for (int pass = 0; pass < 8; ++pass) {
    int c4 = (xc + pass * 4) << 2;
    *(float4*)&xs[xk][c4] =
        make_float4(xv[pass][0], xv[pass][1], xv[pass][2], xv[pass][3]);
  }
  as[ak + 0][ap_] = a0v.x; as[ak + 1][ap_] = a0v.y;
  as[ak + 2][ap_] = a0v.z; as[ak + 3][ap_] = a0v.w;
  as[ak + 32][ap_] = a1v.x; as[ak + 33][ap_] = a1v.y;
  as[ak + 34][ap_] = a1v.z; as[ak + 35][ap_] = a1v.w;
  __syncthreads();

  for (int ks = 0; ks < 512; ks += 64) {
    bool more = (ks + 64 < 512);
    if (more) {  // issue next chunk's loads early
#pragma unroll
      for (int pass = 0; pass < 8; ++pass) {
        int c4 = (xc + pass * 4) << 2;
#pragma unroll
        for (int i = 0; i < 4; ++i)
          xv[pass][i] = xb[(size_t)(c4 + i) * NN + ks + 64 + xk];
      }
      a0v = *(const float4*)&ab[(size_t)ap_ * NN + ks + 64 + ak];
      a1v = *(const float4*)&ab[(size_t)ap_ * NN + ks + 64 + ak + 32];
    }
#pragma unroll 8
    for (int k = 0; k < 64; ++k) {
      float4 xvv = *(const float4*)&xs[k][cq];
      float4 avv = *(const float4*)&as[k][pq];  // broadcast
      acc[0]  = fmaf(avv.x, xvv.x, acc[0]);
      acc[1]  = fmaf(avv.x, xvv.y, acc[1]);
      acc[2]  = fmaf(avv.x, xvv.z, acc[2]);
      acc[3]  = fmaf(avv.x, xvv.w, acc[3]);
      acc[4]  = fmaf(avv.y, xvv.x, acc[4]);
      acc[5]  = fmaf(avv.y, xvv.y, acc[5]);
      acc[6]  = fmaf(avv.y, xvv.z, acc[6]);
      acc[7]  = fmaf(avv.y, xvv.w, acc[7]);
      acc[8]  = fmaf(avv.z, xvv.x, acc[8]);
      acc[9]  = fmaf(avv.z, xvv.y, acc[9]);
      acc[10] = fmaf(avv.z, xvv.z, acc[10]);
      acc[11] = fmaf(avv.z, xvv.w, acc[11]);
      acc[12] = fmaf(avv.w, xvv.x, acc[12]);
      acc[13] = fmaf(avv.w, xvv.y, acc[13]);
      acc[14] = fmaf(avv.w, xvv.z, acc[14]);
      acc[15] = fmaf(avv.w, xvv.w, acc[15]);
    }
    if (more) {
      __syncthreads();
#pragma unroll
      for (int pass = 0; pass < 8; ++pass) {
        int c4 = (xc + pass * 4) << 2;
        *(float4*)&xs[xk][c4] =
            make_float4(xv[pass][0], xv[pass][1], xv[pass][2], xv[pass][3]);
      }
      as[ak + 0][ap_] = a0v.x; as[ak + 1][ap_] = a0v.y;
      as[ak + 2][ap_] = a0v.z; as[ak + 3][ap_] = a0v.w;
      as[ak + 32][ap_] = a1v.x; as[ak + 33][ap_] = a1v.y;
      as[ak + 34][ap_] = a1v.z; as[ak + 35][ap_] = a1v.w;
      __syncthreads();
    }
  }

  // owned (non-atomic) partial stores: qx_part[kc][b][p][c]
#pragma unroll
  for (int i = 0; i < 4; ++i) {
    float* q = qx_part +
        (((size_t)kc * BB + b) * PP + pq + i) * CC + ct * 128 + cq;
    *(float4*)q = make_float4(acc[i * 4 + 0], acc[i * 4 + 1],
                              acc[i * 4 + 2], acc[i * 4 + 3]);
  }
}

// ---------------------------------------------------------------------------
// finalize: qx = sum_kc qx_part; out = (qx/max(sum_ass,1e-5) - centers)/sigma;
// L2-normalize over c; write transposed out_t[b][c][p].
// block per (b,p), 256 threads, 2 c each.
// ---------------------------------------------------------------------------
__global__ __launch_bounds__(256) void finalize_kernel(
    const float* __restrict__ qx_part, const float* __restrict__ w,
    const float* __restrict__ beta, const float* __restrict__ sum_ass,
    float* __restrict__ out_t) {
  int b = blockIdx.x >> 5;
  int p = blockIdx.x & 31;
  int tid = threadIdx.x;
  int wave = tid >> 6, lane = tid & 63;

  float inv_sa = 1.f / fmaxf(sum_ass[b * PP + p], 1e-5f);
  float rsig = rsqrtf(0.5f * beta[p]);

  int c0 = tid, c1 = tid + 256;
  float q0 = 0.f, q1 = 0.f;
#pragma unroll
  for (int kc = 0; kc < 8; ++kc) {
    const float* row = qx_part + (((size_t)kc * BB + b) * PP + p) * CC;
    q0 += row[c0];
    q1 += row[c1];
  }
  const float* wrow = w + (size_t)p * CC;
  float t0 = (q0 * inv_sa - wrow[c0]) * rsig;
  float t1 = (q1 * inv_sa - wrow[c1]) * rsig;

  float nr = t0 * t0 + t1 * t1;
#pragma unroll
  for (int off = 32; off; off >>= 1) nr += __shfl_down(nr, off);
  __shared__ float red[4];
  if (lane == 0) red[wave] = nr;
  __syncthreads();
  float norm2 = red[0] + red[1] + red[2] + red[3];
  float scale = 1.f / fmaxf(sqrtf(norm2), 1e-12f);

  float* ob = out_t + (size_t)b * CC * PP + p;
  ob[(size_t)c0 * PP] = t0 * scale;
  ob[(size_t)c1 * PP] = t1 * scale;
}

// ---------------------------------------------------------------------------
extern "C" void kernel_launch(void* const* d_in, const int* in_sizes, int n_in,
                              void* d_out, int out_size, void* d_ws,
                              size_t ws_size, hipStream_t stream) {
  const float* x = (const float*)d_in[0];   // [B,C,H,W]
  const float* w = (const float*)d_in[1];   // [P,C,1,1]
  const float* sf = (const float*)d_in[2];  // [P]

  float* out_t = (float*)d_out;                  // [B,C,P]
  float* assign = out_t + (size_t)BB * CC * PP;  // [B,P,N]

  float* ws = (float*)d_ws;
  float* beta = ws;           // 32
  float* rbeta = ws + 32;     // 32
  float* csq = ws + 64;       // 32
  float* sum_ass = ws + 96;   // 512
  float* qx_part = ws + 608;  // 8 * B * P * C = 2,097,152 floats (8 MB)

  prep_kernel<<<PP, 64, 0, stream>>>(w, sf, beta, rbeta, csq, sum_ass);
  assign_kernel<<<BB * 32, 256, 0, stream>>>(x, w, rbeta, csq, assign,
                                             sum_ass);
  qx_kernel<<<dim3(32, BB), 256, 0, stream>>>(x, assign, qx_part);
  finalize_kernel<<<BB * PP, 256, 0, stream>>>(qx_part, w, beta, sum_ass,
                                               out_t);
}

// Round 6
// 87.668 us; speedup vs baseline: 1.4324x; 1.1533x over previous
//
#include <hip/hip_runtime.h>

constexpr int BB = 16;     // batch
constexpr int CC = 512;    // channels
constexpr int PP = 32;     // clusters
constexpr int NN = 4096;   // H*W
constexpr int TN = 128;    // assign n-tile per block

using f32x4 = __attribute__((ext_vector_type(4))) float;
using bf16x8 = __attribute__((ext_vector_type(8))) short;

__device__ __forceinline__ ushort f2bf(float f) {
  unsigned u = __builtin_bit_cast(unsigned, f);
  u += 0x7FFFu + ((u >> 16) & 1u);   // round-to-nearest-even
  return (ushort)(u >> 16);
}

// ---------------------------------------------------------------------------
// prep: beta = sigmoid(sf), rbeta = 1/beta, csq[p] = |centers_p|^2.
// Also zeroes sum_ass.
// ---------------------------------------------------------------------------
__global__ __launch_bounds__(64) void prep_kernel(
    const float* __restrict__ w, const float* __restrict__ sf,
    float* __restrict__ beta, float* __restrict__ rbeta,
    float* __restrict__ csq, float* __restrict__ sum_ass) {
  int p = blockIdx.x;
  int t = threadIdx.x;
  if (t < 16) sum_ass[p * 16 + t] = 0.f;
  float s = 0.f;
  for (int i = t; i < CC; i += 64) {
    float v = w[p * CC + i];
    s = fmaf(v, v, s);
  }
#pragma unroll
  for (int off = 32; off; off >>= 1) s += __shfl_down(s, off);
  if (t == 0) {
    csq[p] = s;
    float e = __expf(-sf[p]);
    rbeta[p] = 1.f + e;            // 1/beta
    beta[p] = 1.f / (1.f + e);     // beta
  }
}

// ---------------------------------------------------------------------------
// assign as LDS-tiled GEMM, software-pipelined (unchanged from R5, passing).
// ---------------------------------------------------------------------------
__global__ __launch_bounds__(256) void assign_kernel(
    const float* __restrict__ x, const float* __restrict__ w,
    const float* __restrict__ rbeta, const float* __restrict__ csq,
    float* __restrict__ assign_out, float* __restrict__ sum_ass) {
  __shared__ float xs[64][132];    // x chunk [c][n] 33.8 KB (reused as lgs)
  __shared__ float cs[64][36];     // centers chunk [c][p] 9.2 KB
  __shared__ float xsq_p[8][TN];   // xsq partials per c-group, 4 KB

  int tid = threadIdx.x;
  int b = blockIdx.x >> 5;
  int n0 = (blockIdx.x & 31) * TN;

  int sc = tid >> 5;            // x staging row group 0..7
  int sn = (tid & 31) << 2;     // x staging n-quad
  int sp = tid >> 3;            // w staging p 0..31
  int sk = (tid & 7) << 2;      // w staging c-quad 0..28

  int nq = (tid & 31) << 2;     // compute n offset 0..124
  int pq = (tid >> 5) << 2;     // compute p offset 0..28

  const float* xb = x + (size_t)b * CC * NN + n0;

  float acc[16];
#pragma unroll
  for (int i = 0; i < 16; ++i) acc[i] = 0.f;
  float xq0 = 0.f, xq1 = 0.f, xq2 = 0.f, xq3 = 0.f;

  float4 xr[8], w0v, w1v;
#pragma unroll
  for (int ps = 0; ps < 8; ++ps)
    xr[ps] = *(const float4*)&xb[(size_t)(sc + ps * 8) * NN + sn];
  w0v = *(const float4*)&w[(size_t)sp * CC + sk];
  w1v = *(const float4*)&w[(size_t)sp * CC + sk + 32];
#pragma unroll
  for (int ps = 0; ps < 8; ++ps) {
    *(float4*)&xs[sc + ps * 8][sn] = xr[ps];
    xq0 = fmaf(xr[ps].x, xr[ps].x, xq0);
    xq1 = fmaf(xr[ps].y, xr[ps].y, xq1);
    xq2 = fmaf(xr[ps].z, xr[ps].z, xq2);
    xq3 = fmaf(xr[ps].w, xr[ps].w, xq3);
  }
  cs[sk + 0][sp] = w0v.x; cs[sk + 1][sp] = w0v.y;
  cs[sk + 2][sp] = w0v.z; cs[sk + 3][sp] = w0v.w;
  cs[sk + 32][sp] = w1v.x; cs[sk + 33][sp] = w1v.y;
  cs[sk + 34][sp] = w1v.z; cs[sk + 35][sp] = w1v.w;
  __syncthreads();

  for (int c0 = 0; c0 < CC; c0 += 64) {
    bool more = (c0 + 64 < CC);
    if (more) {
#pragma unroll
      for (int ps = 0; ps < 8; ++ps)
        xr[ps] = *(const float4*)&xb[(size_t)(c0 + 64 + sc + ps * 8) * NN + sn];
      w0v = *(const float4*)&w[(size_t)sp * CC + c0 + 64 + sk];
      w1v = *(const float4*)&w[(size_t)sp * CC + c0 + 64 + sk + 32];
    }
#pragma unroll 8
    for (int k = 0; k < 64; ++k) {
      float4 xv = *(const float4*)&xs[k][nq];
      float4 av = *(const float4*)&cs[k][pq];  // broadcast
      acc[0]  = fmaf(av.x, xv.x, acc[0]);
      acc[1]  = fmaf(av.x, xv.y, acc[1]);
      acc[2]  = fmaf(av.x, xv.z, acc[2]);
      acc[3]  = fmaf(av.x, xv.w, acc[3]);
      acc[4]  = fmaf(av.y, xv.x, acc[4]);
      acc[5]  = fmaf(av.y, xv.y, acc[5]);
      acc[6]  = fmaf(av.y, xv.z, acc[6]);
      acc[7]  = fmaf(av.y, xv.w, acc[7]);
      acc[8]  = fmaf(av.z, xv.x, acc[8]);
      acc[9]  = fmaf(av.z, xv.y, acc[9]);
      acc[10] = fmaf(av.z, xv.z, acc[10]);
      acc[11] = fmaf(av.z, xv.w, acc[11]);
      acc[12] = fmaf(av.w, xv.x, acc[12]);
      acc[13] = fmaf(av.w, xv.y, acc[13]);
      acc[14] = fmaf(av.w, xv.z, acc[14]);
      acc[15] = fmaf(av.w, xv.w, acc[15]);
    }
    if (more) {
      __syncthreads();
#pragma unroll
      for (int ps = 0; ps < 8; ++ps) {
        *(float4*)&xs[sc + ps * 8][sn] = xr[ps];
        xq0 = fmaf(xr[ps].x, xr[ps].x, xq0);
        xq1 = fmaf(xr[ps].y, xr[ps].y, xq1);
        xq2 = fmaf(xr[ps].z, xr[ps].z, xq2);
        xq3 = fmaf(xr[ps].w, xr[ps].w, xq3);
      }
      cs[sk + 0][sp] = w0v.x; cs[sk + 1][sp] = w0v.y;
      cs[sk + 2][sp] = w0v.z; cs[sk + 3][sp] = w0v.w;
      cs[sk + 32][sp] = w1v.x; cs[sk + 33][sp] = w1v.y;
      cs[sk + 34][sp] = w1v.z; cs[sk + 35][sp] = w1v.w;
      __syncthreads();
    }
  }

  *(float4*)&xsq_p[sc][sn] = make_float4(xq0, xq1, xq2, xq3);
  __syncthreads();

  float xs0 = 0.f, xs1 = 0.f, xs2 = 0.f, xs3 = 0.f;
#pragma unroll
  for (int g = 0; g < 8; ++g) {
    float4 v = *(const float4*)&xsq_p[g][nq];
    xs0 += v.x; xs1 += v.y; xs2 += v.z; xs3 += v.w;
  }

  float* lgs = &xs[0][0];  // [128][37]
#pragma unroll
  for (int j = 0; j < 4; ++j) {
    float csj = csq[pq + j], rbj = rbeta[pq + j];
    lgs[(nq + 0) * 37 + pq + j] = fminf(2.f * acc[j * 4 + 0] - xs0 - csj, 0.f) * rbj;
    lgs[(nq + 1) * 37 + pq + j] = fminf(2.f * acc[j * 4 + 1] - xs1 - csj, 0.f) * rbj;
    lgs[(nq + 2) * 37 + pq + j] = fminf(2.f * acc[j * 4 + 2] - xs2 - csj, 0.f) * rbj;
    lgs[(nq + 3) * 37 + pq + j] = fminf(2.f * acc[j * 4 + 3] - xs3 - csj, 0.f) * rbj;
  }
  __syncthreads();

  if (tid < TN) {
    float v[PP];
    float m = -3.4e38f;
#pragma unroll
    for (int p = 0; p < PP; ++p) {
      v[p] = lgs[tid * 37 + p];
      m = fmaxf(m, v[p]);
    }
    float s = 0.f;
#pragma unroll
    for (int p = 0; p < PP; ++p) {
      v[p] = __expf(v[p] - m);
      s += v[p];
    }
    float inv = 1.f / s;
#pragma unroll
    for (int p = 0; p < PP; ++p) lgs[tid * 37 + p] = v[p] * inv;
  }
  __syncthreads();

#pragma unroll
  for (int rep = 0; rep < 4; ++rep) {
    int idx = tid + rep * 256;
    int p = idx >> 5;
    int nf = (idx & 31) << 2;
    float a0 = lgs[(nf + 0) * 37 + p];
    float a1 = lgs[(nf + 1) * 37 + p];
    float a2 = lgs[(nf + 2) * 37 + p];
    float a3 = lgs[(nf + 3) * 37 + p];
    *(float4*)&assign_out[((size_t)b * PP + p) * NN + n0 + nf] =
        make_float4(a0, a1, a2, a3);
    float s = (a0 + a1) + (a2 + a3);
#pragma unroll
    for (int off = 16; off; off >>= 1) s += __shfl_down(s, off, 32);
    if ((tid & 31) == 0) atomicAdd(&sum_ass[b * PP + p], s);
  }
}

// ---------------------------------------------------------------------------
// qx via bf16 MFMA: qx_part[kc][b][p][c] = sum_{n in chunk} a[p][n]*x[c][n].
// D[p][c] = A[p,n] · B[n,c];  A = assign (M=32p), B = x^T (N=128c), K = n.
// grid (32 = 8 kchunks x 4 ctiles, 16 b), block 256 = 4 waves.
// Per inner-chunk (128 n): stage x fp32->bf16 LDS [128c][136], a -> [32p][136].
// Wave wv owns c in [32wv, 32wv+32): 2 c-frags x 2 p-frags, 16 MFMA/chunk.
// Frag maps (16x16x32): A lane: m=l&15, k=(l>>4)*8+j ; B lane: n=l&15, same k.
// C/D: col(c)=l&15, row(p)=(l>>4)*4+i  [HW-verified layout].
// ---------------------------------------------------------------------------
__global__ __launch_bounds__(256) void qx_kernel(
    const float* __restrict__ x, const float* __restrict__ assign,
    float* __restrict__ qx_part) {
  __shared__ ushort xbf[128][136];  // [c_local][n_local] bf16, 34.8 KB
  __shared__ ushort abf[32][136];   // [p][n_local] bf16, 8.7 KB

  int tid = threadIdx.x;
  int b = blockIdx.y;
  int kc = blockIdx.x >> 2;   // 0..7: k-chunk of 512 n
  int ct = blockIdx.x & 3;    // 0..3: c-tile of 128
  int wv = tid >> 6, lane = tid & 63;
  int l15 = lane & 15, lg = lane >> 4;

  const float* xb = x + ((size_t)b * CC + ct * 128) * NN + kc * 512;
  const float* ab = assign + (size_t)b * PP * NN + kc * 512;

  int c_s = tid >> 1;            // x staging row 0..127
  int nh  = (tid & 1) << 6;      // n half: 0 or 64
  int p_s = tid >> 3;            // a staging p 0..31
  int na  = (tid & 7) << 4;      // a staging n off 0..112

  f32x4 acc[2][2];
#pragma unroll
  for (int i = 0; i < 2; ++i)
#pragma unroll
    for (int j = 0; j < 2; ++j) acc[i][j] = {0.f, 0.f, 0.f, 0.f};

  for (int ch = 0; ch < 4; ++ch) {   // 4 inner chunks of 128 n
    int nb = ch * 128;
    if (ch) __syncthreads();   // all waves done reading previous chunk
    // stage x (64 f32/thread in two halves of 8 float4)
#pragma unroll
    for (int h = 0; h < 2; ++h) {
      float4 v[8];
#pragma unroll
      for (int i = 0; i < 8; ++i)
        v[i] = *(const float4*)&xb[(size_t)c_s * NN + nb + nh + h * 32 + i * 4];
#pragma unroll
      for (int i = 0; i < 8; ++i) {
        ushort4 u;
        u.x = f2bf(v[i].x); u.y = f2bf(v[i].y);
        u.z = f2bf(v[i].z); u.w = f2bf(v[i].w);
        *(ushort4*)&xbf[c_s][nh + h * 32 + i * 4] = u;
      }
    }
    // stage a (16 f32/thread)
    {
      float4 v[4];
#pragma unroll
      for (int i = 0; i < 4; ++i)
        v[i] = *(const float4*)&ab[(size_t)p_s * NN + nb + na + i * 4];
#pragma unroll
      for (int i = 0; i < 4; ++i) {
        ushort4 u;
        u.x = f2bf(v[i].x); u.y = f2bf(v[i].y);
        u.z = f2bf(v[i].z); u.w = f2bf(v[i].w);
        *(ushort4*)&abf[p_s][na + i * 4] = u;
      }
    }
    __syncthreads();
#pragma unroll
    for (int ks = 0; ks < 4; ++ks) {   // k-steps of 32 n
      int nf = ks * 32 + lg * 8;
      bf16x8 a0 = *(const bf16x8*)&abf[l15][nf];
      bf16x8 a1 = *(const bf16x8*)&abf[16 + l15][nf];
      bf16x8 b0 = *(const bf16x8*)&xbf[wv * 32 + l15][nf];
      bf16x8 b1 = *(const bf16x8*)&xbf[wv * 32 + 16 + l15][nf];
      acc[0][0] = __builtin_amdgcn_mfma_f32_16x16x32_bf16(a0, b0, acc[0][0], 0, 0, 0);
      acc[0][1] = __builtin_amdgcn_mfma_f32_16x16x32_bf16(a0, b1, acc[0][1], 0, 0, 0);
      acc[1][0] = __builtin_amdgcn_mfma_f32_16x16x32_bf16(a1, b0, acc[1][0], 0, 0, 0);
      acc[1][1] = __builtin_amdgcn_mfma_f32_16x16x32_bf16(a1, b1, acc[1][1], 0, 0, 0);
    }
  }

  // store: p = pf*16 + lg*4 + i ; c = ct*128 + wv*32 + cf*16 + l15
#pragma unroll
  for (int pf = 0; pf < 2; ++pf)
#pragma unroll
    for (int cf = 0; cf < 2; ++cf)
#pragma unroll
      for (int i = 0; i < 4; ++i) {
        int p = pf * 16 + lg * 4 + i;
        int c = ct * 128 + wv * 32 + cf * 16 + l15;
        qx_part[(((size_t)kc * BB + b) * PP + p) * CC + c] = acc[pf][cf][i];
      }
}

// ---------------------------------------------------------------------------
// finalize: qx = sum_kc qx_part; out = (qx/max(sum_ass,1e-5) - centers)/sigma;
// L2-normalize over c; write transposed out_t[b][c][p].
// ---------------------------------------------------------------------------
__global__ __launch_bounds__(256) void finalize_kernel(
    const float* __restrict__ qx_part, const float* __restrict__ w,
    const float* __restrict__ beta, const float* __restrict__ sum_ass,
    float* __restrict__ out_t) {
  int b = blockIdx.x >> 5;
  int p = blockIdx.x & 31;
  int tid = threadIdx.x;
  int wave = tid >> 6, lane = tid & 63;

  float inv_sa = 1.f / fmaxf(sum_ass[b * PP + p], 1e-5f);
  float rsig = rsqrtf(0.5f * beta[p]);

  int c0 = tid, c1 = tid + 256;
  float q0 = 0.f, q1 = 0.f;
#pragma unroll
  for (int kc = 0; kc < 8; ++kc) {
    const float* row = qx_part + (((size_t)kc * BB + b) * PP + p) * CC;
    q0 += row[c0];
    q1 += row[c1];
  }
  const float* wrow = w + (size_t)p * CC;
  float t0 = (q0 * inv_sa - wrow[c0]) * rsig;
  float t1 = (q1 * inv_sa - wrow[c1]) * rsig;

  float nr = t0 * t0 + t1 * t1;
#pragma unroll
  for (int off = 32; off; off >>= 1) nr += __shfl_down(nr, off);
  __shared__ float red[4];
  if (lane == 0) red[wave] = nr;
  __syncthreads();
  float norm2 = red[0] + red[1] + red[2] + red[3];
  float scale = 1.f / fmaxf(sqrtf(norm2), 1e-12f);

  float* ob = out_t + (size_t)b * CC * PP + p;
  ob[(size_t)c0 * PP] = t0 * scale;
  ob[(size_t)c1 * PP] = t1 * scale;
}

// ---------------------------------------------------------------------------
extern "C" void kernel_launch(void* const* d_in, const int* in_sizes, int n_in,
                              void* d_out, int out_size, void* d_ws,
                              size_t ws_size, hipStream_t stream) {
  const float* x = (const float*)d_in[0];   // [B,C,H,W]
  const float* w = (const float*)d_in[1];   // [P,C,1,1]
  const float* sf = (const float*)d_in[2];  // [P]

  float* out_t = (float*)d_out;                  // [B,C,P]
  float* assign = out_t + (size_t)BB * CC * PP;  // [B,P,N]

  float* ws = (float*)d_ws;
  float* beta = ws;           // 32
  float* rbeta = ws + 32;     // 32
  float* csq = ws + 64;       // 32
  float* sum_ass = ws + 96;   // 512
  float* qx_part = ws + 608;  // 8 * B * P * C = 2,097,152 floats (8 MB)

  prep_kernel<<<PP, 64, 0, stream>>>(w, sf, beta, rbeta, csq, sum_ass);
  assign_kernel<<<BB * 32, 256, 0, stream>>>(x, w, rbeta, csq, assign,
                                             sum_ass);
  qx_kernel<<<dim3(32, BB), 256, 0, stream>>>(x, assign, qx_part);
  finalize_kernel<<<BB * PP, 256, 0, stream>>>(qx_part, w, beta, sum_ass,
                                               out_t);
}